// Round 6
// baseline (757.683 us; speedup 1.0000x reference)
//
#include <hip/hip_runtime.h>
#include <hip/hip_bf16.h>

// Problem constants (from reference)
constexpr int Bc  = 2;
constexpr int Tc  = 2048;
constexpr int Dc  = 2048;
constexpr int Hc  = 32;
constexpr int KVc = 8;
constexpr int HDc = 64;
constexpr int Mrows = Bc * Tc;          // 4096
constexpr int QKVW  = 3072;             // fused q|k|v width
constexpr float SCALE = 0.125f;         // 1/sqrt(64)

typedef __attribute__((ext_vector_type(8))) short  bf16x8;
typedef __attribute__((ext_vector_type(4))) short  short4v;
typedef __attribute__((ext_vector_type(4))) float  f32x4;

__device__ __forceinline__ short f2bf(float f) {     // fp32 -> bf16 (RNE)
    unsigned u = __builtin_bit_cast(unsigned, f);
    unsigned r = (u + 0x7FFFu + ((u >> 16) & 1u)) >> 16;
    return (short)(unsigned short)r;
}

__device__ __forceinline__ void load_lds16(const void* g, void* l) {
    __builtin_amdgcn_global_load_lds(
        (const __attribute__((address_space(1))) unsigned int*)g,
        (__attribute__((address_space(3))) unsigned int*)l,
        16, 0, 0);
}

// ---------------------------------------------------------------------------
// fp32 -> bf16 elementwise convert (n multiple of 8)
// ---------------------------------------------------------------------------
__global__ void conv_bf16(const float* __restrict__ in, short* __restrict__ out, int n) {
    int i = (blockIdx.x * blockDim.x + threadIdx.x) * 8;
    if (i >= n) return;
    f32x4 a = *(const f32x4*)(in + i);
    f32x4 b = *(const f32x4*)(in + i + 4);
    bf16x8 o;
    o[0] = f2bf(a[0]); o[1] = f2bf(a[1]); o[2] = f2bf(a[2]); o[3] = f2bf(a[3]);
    o[4] = f2bf(b[0]); o[5] = f2bf(b[1]); o[6] = f2bf(b[2]); o[7] = f2bf(b[3]);
    *(bf16x8*)(out + i) = o;
}

// ---------------------------------------------------------------------------
// Transpose + convert: in fp32 [K x N] row-major -> out bf16 rows = N-columns.
// ---------------------------------------------------------------------------
__global__ __launch_bounds__(256) void transpose_conv(const float* __restrict__ in,
                                                      short* __restrict__ out,
                                                      int N, int ldo, int n0r) {
    __shared__ float T[64][68];
    const int k0 = blockIdx.y * 64;
    const int n0 = blockIdx.x * 64;
    const int t  = threadIdx.x;
    const int c4 = (t & 15) * 4;
    const int rr = t >> 4;
#pragma unroll
    for (int r = 0; r < 4; ++r) {
        int k = rr + 16 * r;
        float4 v = *(const float4*)(in + (size_t)(k0 + k) * N + n0 + c4);
        *(float4*)&T[k][c4] = v;
    }
    __syncthreads();
#pragma unroll
    for (int r = 0; r < 4; ++r) {
        int n = rr + 16 * r;
        short4v s;
        s[0] = f2bf(T[c4 + 0][n]); s[1] = f2bf(T[c4 + 1][n]);
        s[2] = f2bf(T[c4 + 2][n]); s[3] = f2bf(T[c4 + 3][n]);
        *(short4v*)(out + (size_t)(n0r + n0 + n) * ldo + k0 + c4) = s;
    }
}

// ---------------------------------------------------------------------------
// bf16 MFMA GEMM (m97 structure) with XCD-aware block swizzle.
// C[M,N] fp32 = A[M,K] @ Bt[N,K]^T.  Grid blocks must be divisible by 8.
// ---------------------------------------------------------------------------
__global__ __launch_bounds__(256) void gemm_mfma(const short* __restrict__ A,
                                                 const short* __restrict__ Bt,
                                                 float* __restrict__ C,
                                                 int M, int N, int K) {
    __shared__ short Al[128 * 64];
    __shared__ short Bl[128 * 64];
    const int tid = threadIdx.x;
    const int l  = tid & 63;
    const int w  = tid >> 6;
    const int lr = l & 15;
    const int lg = l >> 4;
    const int wm = w >> 1, wn = w & 1;

    const int nwg = gridDim.x * gridDim.y;
    const int bid0 = blockIdx.y * gridDim.x + blockIdx.x;
    const int cpx = nwg >> 3;
    const int swz = (bid0 & 7) * cpx + (bid0 >> 3);
    const int bm = (swz / gridDim.x) * 128;
    const int bn = (swz % gridDim.x) * 128;

    f32x4 acc[4][4];
#pragma unroll
    for (int i = 0; i < 4; ++i)
#pragma unroll
        for (int j = 0; j < 4; ++j) acc[i][j] = f32x4{0.f, 0.f, 0.f, 0.f};

    const int srow_off = l >> 3;
    const int sunit    = l & 7;

    for (int k0 = 0; k0 < K; k0 += 64) {
        __syncthreads();
#pragma unroll
        for (int j = 0; j < 4; ++j) {
            const int q   = w + 4 * j;
            const int row = 8 * q + srow_off;
            const int ug  = sunit ^ (row & 7);
            load_lds16(A  + (size_t)(bm + row) * K + k0 + ug * 8, (short*)Al + 512 * q);
            load_lds16(Bt + (size_t)(bn + row) * K + k0 + ug * 8, (short*)Bl + 512 * q);
        }
        __syncthreads();

#pragma unroll
        for (int ks = 0; ks < 2; ++ks) {
            bf16x8 af[4], bf[4];
#pragma unroll
            for (int mb = 0; mb < 4; ++mb) {
                const int row = wm * 64 + mb * 16 + lr;
                const int u   = (ks * 4 + lg) ^ (row & 7);
                af[mb] = *(const bf16x8*)(Al + row * 64 + u * 8);
            }
#pragma unroll
            for (int nb = 0; nb < 4; ++nb) {
                const int row = wn * 64 + nb * 16 + lr;
                const int u   = (ks * 4 + lg) ^ (row & 7);
                bf[nb] = *(const bf16x8*)(Bl + row * 64 + u * 8);
            }
#pragma unroll
            for (int mb = 0; mb < 4; ++mb)
#pragma unroll
                for (int nb = 0; nb < 4; ++nb)
                    acc[mb][nb] = __builtin_amdgcn_mfma_f32_16x16x32_bf16(
                        af[mb], bf[nb], acc[mb][nb], 0, 0, 0);
        }
    }

#pragma unroll
    for (int mb = 0; mb < 4; ++mb)
#pragma unroll
        for (int r = 0; r < 4; ++r) {
            const int row = bm + wm * 64 + mb * 16 + lg * 4 + r;
            float* cp = C + (size_t)row * N + bn + wn * 64 + lr;
#pragma unroll
            for (int nb = 0; nb < 4; ++nb) cp[nb * 16] = acc[mb][nb][r];
        }
}

// ---------------------------------------------------------------------------
// RoPE + pack: qkv fp32 [Mrows][3072] -> qb bf16 [b][h][t][64] (scaled),
// kb bf16 [b][g][t][64].
// ---------------------------------------------------------------------------
__global__ void rope_pack_qk(const float* __restrict__ qkv,
                             const float* __restrict__ cosT,
                             const float* __restrict__ sinT,
                             short* __restrict__ qb, short* __restrict__ kb,
                             int total) {
    int idx = blockIdx.x * blockDim.x + threadIdx.x;
    if (idx >= total) return;
    int d   = idx & 31;
    int hh  = (idx >> 5) % 40;
    int row = idx / (32 * 40);
    int t   = row & (Tc - 1);
    int b   = row >> 11;
    float c = cosT[t * HDc + d];
    float s = sinT[t * HDc + d];
    if (hh < 32) {
        const float* p = qkv + (size_t)row * QKVW + hh * 64;
        float x0 = p[d], x1 = p[d + 32];
        short* qp = qb + (((size_t)(b * Hc + hh) * Tc + t) * 64);
        qp[d]      = f2bf((x0 * c - x1 * s) * SCALE);
        qp[d + 32] = f2bf((x1 * c + x0 * s) * SCALE);
    } else {
        int g = hh - 32;
        const float* p = qkv + (size_t)row * QKVW + 2048 + g * 64;
        float x0 = p[d], x1 = p[d + 32];
        short* kp = kb + (((size_t)(b * KVc + g) * Tc + t) * 64);
        kp[d]      = f2bf(x0 * c - x1 * s);
        kp[d + 32] = f2bf(x1 * c + x0 * s);
    }
}

// ---------------------------------------------------------------------------
// V transpose + convert: qkv fp32 v-section -> vtb bf16 [b][g][d][T].
// ---------------------------------------------------------------------------
__global__ __launch_bounds__(256) void pack_vt(const float* __restrict__ qkv,
                                               short* __restrict__ vtb) {
    __shared__ float T[64][68];
    const int t0 = blockIdx.x * 64;
    const int g  = blockIdx.y;
    const int b  = blockIdx.z;
    const int tt = threadIdx.x;
    const int c4 = (tt & 15) * 4;
    const int rr = tt >> 4;
    const float* src = qkv + 2560 + g * 64;
#pragma unroll
    for (int r = 0; r < 4; ++r) {
        int t = rr + 16 * r;
        float4 v = *(const float4*)(src + (size_t)(b * Tc + t0 + t) * QKVW + c4);
        *(float4*)&T[t][c4] = v;
    }
    __syncthreads();
    short* dst = vtb + ((size_t)(b * KVc + g) * 64) * Tc;
#pragma unroll
    for (int r = 0; r < 4; ++r) {
        int d = rr + 16 * r;
        short4v s;
        s[0] = f2bf(T[c4 + 0][d]); s[1] = f2bf(T[c4 + 1][d]);
        s[2] = f2bf(T[c4 + 2][d]); s[3] = f2bf(T[c4 + 3][d]);
        *(short4v*)(dst + (size_t)d * Tc + t0 + c4) = s;
    }
}

// ---------------------------------------------------------------------------
// Latency-optimized bf16 MFMA flash attention.
// 256-thr block = 4 INDEPENDENT waves (no barriers); wave w owns q-tile
// j = bx*4+w (16 rows).  V frags for the current step are issued before
// QK^T (latency hides under MFMA+softmax); K frags for step st+1 are
// prefetched into a register double-buffer (named arrays, unroll-by-2)
// during the current softmax.  Only LDS: per-wave 16x72 P relay.
// ---------------------------------------------------------------------------
__global__ __launch_bounds__(256, 3) void attn_gqa(const short* __restrict__ qb,
                                                   const short* __restrict__ kb,
                                                   const short* __restrict__ vtb,
                                                   short* __restrict__ yb) {
    __shared__ short Ps[4][16][72];
    const int tid = threadIdx.x;
    const int l  = tid & 63;
    const int w  = tid >> 6;
    const int lr = l & 15;
    const int lg = l >> 4;
    const int j  = (blockIdx.x << 2) | w;     // q-tile 0..127
    const int h  = blockIdx.y;
    const int b  = blockIdx.z;
    const int g  = h >> 2;
    const int qt0 = j * 16;

    const short* qhb = qb  + ((size_t)(b * Hc  + h) * Tc) * 64;
    const short* khb = kb  + ((size_t)(b * KVc + g) * Tc) * 64;
    const short* vhb = vtb + ((size_t)(b * KVc + g) * 64) * Tc;

    const bf16x8 qf0 = *(const bf16x8*)(qhb + (size_t)(qt0 + lr) * 64 + lg * 8);
    const bf16x8 qf1 = *(const bf16x8*)(qhb + (size_t)(qt0 + lr) * 64 + 32 + lg * 8);

    f32x4 o[4];
#pragma unroll
    for (int i = 0; i < 4; ++i) o[i] = f32x4{0.f, 0.f, 0.f, 0.f};
    float mr[4], ls[4];
#pragma unroll
    for (int i = 0; i < 4; ++i) { mr[i] = -1e30f; ls[i] = 0.f; }

    const int nsteps = (qt0 >> 6) + 1;

    bf16x8 kfa[8], kfb[8];      // K fragment double-buffer (compile-time swap)

#pragma unroll
    for (int kbk = 0; kbk < 4; ++kbk) {       // preload step 0
        const short* kr = khb + (size_t)(16 * kbk + lr) * 64;
        kfa[2 * kbk]     = *(const bf16x8*)(kr + lg * 8);
        kfa[2 * kbk + 1] = *(const bf16x8*)(kr + 32 + lg * 8);
    }

    auto step = [&](int st, bf16x8 (&kcur)[8], bf16x8 (&knxt)[8]) {
        const int kv0 = st * 64;

        // ---- V loads issued FIRST: in flight through QK+softmax ----
        bf16x8 vv[8];
#pragma unroll
        for (int ks = 0; ks < 2; ++ks)
#pragma unroll
            for (int db = 0; db < 4; ++db)
                vv[ks * 4 + db] = *(const bf16x8*)(vhb + (size_t)(db * 16 + lr) * Tc
                                                   + kv0 + ks * 32 + lg * 8);

        // ---- S = Q K^T from register K frags ----
        f32x4 c[4];
#pragma unroll
        for (int kbk = 0; kbk < 4; ++kbk) {
            f32x4 acc = f32x4{0.f, 0.f, 0.f, 0.f};
            acc = __builtin_amdgcn_mfma_f32_16x16x32_bf16(qf0, kcur[2 * kbk],     acc, 0, 0, 0);
            acc = __builtin_amdgcn_mfma_f32_16x16x32_bf16(qf1, kcur[2 * kbk + 1], acc, 0, 0, 0);
            c[kbk] = acc;
        }

        // ---- K prefetch for st+1: latency hides under softmax+PV ----
        if (st + 1 < nsteps) {
            const int kn = kv0 + 64;
#pragma unroll
            for (int kbk = 0; kbk < 4; ++kbk) {
                const short* kr = khb + (size_t)(kn + 16 * kbk + lr) * 64;
                knxt[2 * kbk]     = *(const bf16x8*)(kr + lg * 8);
                knxt[2 * kbk + 1] = *(const bf16x8*)(kr + 32 + lg * 8);
            }
        }

        if (st == nsteps - 1) {               // causal mask, diagonal step only
#pragma unroll
            for (int kbk = 0; kbk < 4; ++kbk)
#pragma unroll
                for (int r = 0; r < 4; ++r)
                    if (kv0 + lr + 16 * kbk > qt0 + lg * 4 + r) c[kbk][r] = -1e30f;
        }

        // ---- online softmax ----
#pragma unroll
        for (int r = 0; r < 4; ++r) {
            float tm = fmaxf(fmaxf(c[0][r], c[1][r]), fmaxf(c[2][r], c[3][r]));
            tm = fmaxf(tm, __shfl_xor(tm, 1));
            tm = fmaxf(tm, __shfl_xor(tm, 2));
            tm = fmaxf(tm, __shfl_xor(tm, 4));
            tm = fmaxf(tm, __shfl_xor(tm, 8));
            if (tm > mr[r]) {
                const float corr = __expf(mr[r] - tm);
                mr[r] = tm;
                ls[r] *= corr;
#pragma unroll
                for (int db = 0; db < 4; ++db) o[db][r] *= corr;
            }
            float rs = 0.f;
#pragma unroll
            for (int kbk = 0; kbk < 4; ++kbk) {
                float p = __expf(c[kbk][r] - mr[r]);
                c[kbk][r] = p;
                rs += p;
            }
            rs += __shfl_xor(rs, 1);
            rs += __shfl_xor(rs, 2);
            rs += __shfl_xor(rs, 4);
            rs += __shfl_xor(rs, 8);
            ls[r] += rs;
#pragma unroll
            for (int kbk = 0; kbk < 4; ++kbk)
                Ps[w][lg * 4 + r][lr + 16 * kbk] = f2bf(c[kbk][r]);
        }

        // ---- O += P V (V already in registers) ----
#pragma unroll
        for (int ks = 0; ks < 2; ++ks) {
            bf16x8 pa = *(const bf16x8*)&Ps[w][lr][lg * 8 + ks * 32];
#pragma unroll
            for (int db = 0; db < 4; ++db)
                o[db] = __builtin_amdgcn_mfma_f32_16x16x32_bf16(pa, vv[ks * 4 + db],
                                                                o[db], 0, 0, 0);
        }
    };

    for (int st = 0; st < nsteps; st += 2) {
        step(st, kfa, kfb);
        if (st + 1 < nsteps) step(st + 1, kfb, kfa);
    }

    // ---- epilogue ----
#pragma unroll
    for (int r = 0; r < 4; ++r) {
        const float inv = 1.0f / ls[r];
        short* yp = yb + (size_t)(b * Tc + qt0 + lg * 4 + r) * Dc + h * 64;
#pragma unroll
        for (int db = 0; db < 4; ++db)
            yp[lr + 16 * db] = f2bf(o[db][r] * inv);
    }
}

// ---------------------------------------------------------------------------
extern "C" void kernel_launch(void* const* d_in, const int* in_sizes, int n_in,
                              void* d_out, int out_size, void* d_ws, size_t ws_size,
                              hipStream_t stream) {
    const float* x    = (const float*)d_in[0];
    const float* Wq   = (const float*)d_in[1];
    const float* Wk   = (const float*)d_in[2];
    const float* Wv   = (const float*)d_in[3];
    const float* Wo   = (const float*)d_in[4];
    const float* cosT = (const float*)d_in[5];
    const float* sinT = (const float*)d_in[6];
    float* out = (float*)d_out;

    short* xb    = (short*)d_ws;                            // [4096,2048] bf16
    short* Wqkvt = xb + (size_t)Mrows * Dc;                 // [3072,2048] bf16
    short* Wot   = Wqkvt + (size_t)QKVW * Dc;               // [2048,2048] bf16
    short* ybuf  = Wot + (size_t)Dc * Dc;                   // [4096,2048] bf16
    float* qkv   = (float*)(ybuf + (size_t)Mrows * Dc);     // [4096,3072] f32
    short* qbp = xb;                                        // reuse after QKV GEMM
    short* kbp = Wqkvt;
    short* vtb = Wqkvt + (size_t)Bc * KVc * Tc * 64;

    conv_bf16<<<(Mrows * Dc / 8 + 255) / 256, 256, 0, stream>>>(x, xb, Mrows * Dc);
    transpose_conv<<<dim3(Dc / 64, Dc / 64), 256, 0, stream>>>(Wq, Wqkvt, Dc, Dc, 0);
    transpose_conv<<<dim3(512 / 64, Dc / 64), 256, 0, stream>>>(Wk, Wqkvt, 512, Dc, 2048);
    transpose_conv<<<dim3(512 / 64, Dc / 64), 256, 0, stream>>>(Wv, Wqkvt, 512, Dc, 2560);
    transpose_conv<<<dim3(Dc / 64, Dc / 64), 256, 0, stream>>>(Wo, Wot, Dc, Dc, 0);

    gemm_mfma<<<dim3(QKVW / 128, Mrows / 128), 256, 0, stream>>>(xb, Wqkvt, qkv, Mrows, QKVW, Dc);

    {
        int total = Mrows * (Hc + KVc) * 32;
        rope_pack_qk<<<(total + 255) / 256, 256, 0, stream>>>(qkv, cosT, sinT, qbp, kbp, total);
        pack_vt<<<dim3(Tc / 64, KVc, Bc), 256, 0, stream>>>(qkv, vtb);
    }

    // 4 independent waves / block; wave w -> q-tile bx*4+w
    attn_gqa<<<dim3(32, Hc, Bc), 256, 0, stream>>>(qbp, kbp, vtb, ybuf);

    gemm_mfma<<<dim3(Dc / 128, Mrows / 128), 256, 0, stream>>>(ybuf, Wot, out, Mrows, Dc, Dc);
}

// Round 9
// 470.840 us; speedup vs baseline: 1.6092x; 1.6092x over previous
//
#include <hip/hip_runtime.h>
#include <hip/hip_bf16.h>

// Problem constants (from reference)
constexpr int Bc  = 2;
constexpr int Tc  = 2048;
constexpr int Dc  = 2048;
constexpr int Hc  = 32;
constexpr int KVc = 8;
constexpr int HDc = 64;
constexpr int Mrows = Bc * Tc;          // 4096
constexpr int QKVW  = 3072;             // fused q|k|v width
constexpr float SCALE = 0.125f;         // 1/sqrt(64)

typedef __attribute__((ext_vector_type(8))) short  bf16x8;
typedef __attribute__((ext_vector_type(4))) short  short4v;
typedef __attribute__((ext_vector_type(4))) float  f32x4;

__device__ __forceinline__ short f2bf(float f) {     // fp32 -> bf16 (RNE)
    unsigned u = __builtin_bit_cast(unsigned, f);
    unsigned r = (u + 0x7FFFu + ((u >> 16) & 1u)) >> 16;
    return (short)(unsigned short)r;
}

__device__ __forceinline__ void load_lds16(const void* g, void* l) {
    __builtin_amdgcn_global_load_lds(
        (const __attribute__((address_space(1))) unsigned int*)g,
        (__attribute__((address_space(3))) unsigned int*)l,
        16, 0, 0);
}

// Wave-local LDS ordering fence: prevents the compiler from moving per-lane
// ds_read/ds_write across this point (LDS is in-order per wave in HW, so
// emission order == visibility order).  Zero runtime cost.
__device__ __forceinline__ void lds_fence() {
    __builtin_amdgcn_sched_barrier(0);
    __builtin_amdgcn_wave_barrier();
    __builtin_amdgcn_sched_barrier(0);
}

// ---------------------------------------------------------------------------
// fp32 -> bf16 elementwise convert (n multiple of 8)
// ---------------------------------------------------------------------------
__global__ void conv_bf16(const float* __restrict__ in, short* __restrict__ out, int n) {
    int i = (blockIdx.x * blockDim.x + threadIdx.x) * 8;
    if (i >= n) return;
    f32x4 a = *(const f32x4*)(in + i);
    f32x4 b = *(const f32x4*)(in + i + 4);
    bf16x8 o;
    o[0] = f2bf(a[0]); o[1] = f2bf(a[1]); o[2] = f2bf(a[2]); o[3] = f2bf(a[3]);
    o[4] = f2bf(b[0]); o[5] = f2bf(b[1]); o[6] = f2bf(b[2]); o[7] = f2bf(b[3]);
    *(bf16x8*)(out + i) = o;
}

// ---------------------------------------------------------------------------
// Transpose + convert: in fp32 [K x N] row-major -> out bf16 rows = N-columns.
// ---------------------------------------------------------------------------
__global__ __launch_bounds__(256) void transpose_conv(const float* __restrict__ in,
                                                      short* __restrict__ out,
                                                      int N, int ldo, int n0r) {
    __shared__ float T[64][68];
    const int k0 = blockIdx.y * 64;
    const int n0 = blockIdx.x * 64;
    const int t  = threadIdx.x;
    const int c4 = (t & 15) * 4;
    const int rr = t >> 4;
#pragma unroll
    for (int r = 0; r < 4; ++r) {
        int k = rr + 16 * r;
        float4 v = *(const float4*)(in + (size_t)(k0 + k) * N + n0 + c4);
        *(float4*)&T[k][c4] = v;
    }
    __syncthreads();
#pragma unroll
    for (int r = 0; r < 4; ++r) {
        int n = rr + 16 * r;
        short4v s;
        s[0] = f2bf(T[c4 + 0][n]); s[1] = f2bf(T[c4 + 1][n]);
        s[2] = f2bf(T[c4 + 2][n]); s[3] = f2bf(T[c4 + 3][n]);
        *(short4v*)(out + (size_t)(n0r + n0 + n) * ldo + k0 + c4) = s;
    }
}

// ---------------------------------------------------------------------------
// bf16 MFMA GEMM (m97 structure) with XCD-aware block swizzle.
// ---------------------------------------------------------------------------
__global__ __launch_bounds__(256) void gemm_mfma(const short* __restrict__ A,
                                                 const short* __restrict__ Bt,
                                                 float* __restrict__ C,
                                                 int M, int N, int K) {
    __shared__ short Al[128 * 64];
    __shared__ short Bl[128 * 64];
    const int tid = threadIdx.x;
    const int l  = tid & 63;
    const int w  = tid >> 6;
    const int lr = l & 15;
    const int lg = l >> 4;
    const int wm = w >> 1, wn = w & 1;

    const int nwg = gridDim.x * gridDim.y;
    const int bid0 = blockIdx.y * gridDim.x + blockIdx.x;
    const int cpx = nwg >> 3;
    const int swz = (bid0 & 7) * cpx + (bid0 >> 3);
    const int bm = (swz / gridDim.x) * 128;
    const int bn = (swz % gridDim.x) * 128;

    f32x4 acc[4][4];
#pragma unroll
    for (int i = 0; i < 4; ++i)
#pragma unroll
        for (int j = 0; j < 4; ++j) acc[i][j] = f32x4{0.f, 0.f, 0.f, 0.f};

    const int srow_off = l >> 3;
    const int sunit    = l & 7;

    for (int k0 = 0; k0 < K; k0 += 64) {
        __syncthreads();
#pragma unroll
        for (int j = 0; j < 4; ++j) {
            const int q   = w + 4 * j;
            const int row = 8 * q + srow_off;
            const int ug  = sunit ^ (row & 7);
            load_lds16(A  + (size_t)(bm + row) * K + k0 + ug * 8, (short*)Al + 512 * q);
            load_lds16(Bt + (size_t)(bn + row) * K + k0 + ug * 8, (short*)Bl + 512 * q);
        }
        __syncthreads();

#pragma unroll
        for (int ks = 0; ks < 2; ++ks) {
            bf16x8 af[4], bf[4];
#pragma unroll
            for (int mb = 0; mb < 4; ++mb) {
                const int row = wm * 64 + mb * 16 + lr;
                const int u   = (ks * 4 + lg) ^ (row & 7);
                af[mb] = *(const bf16x8*)(Al + row * 64 + u * 8);
            }
#pragma unroll
            for (int nb = 0; nb < 4; ++nb) {
                const int row = wn * 64 + nb * 16 + lr;
                const int u   = (ks * 4 + lg) ^ (row & 7);
                bf[nb] = *(const bf16x8*)(Bl + row * 64 + u * 8);
            }
#pragma unroll
            for (int mb = 0; mb < 4; ++mb)
#pragma unroll
                for (int nb = 0; nb < 4; ++nb)
                    acc[mb][nb] = __builtin_amdgcn_mfma_f32_16x16x32_bf16(
                        af[mb], bf[nb], acc[mb][nb], 0, 0, 0);
        }
    }

#pragma unroll
    for (int mb = 0; mb < 4; ++mb)
#pragma unroll
        for (int r = 0; r < 4; ++r) {
            const int row = bm + wm * 64 + mb * 16 + lg * 4 + r;
            float* cp = C + (size_t)row * N + bn + wn * 64 + lr;
#pragma unroll
            for (int nb = 0; nb < 4; ++nb) cp[nb * 16] = acc[mb][nb][r];
        }
}

// ---------------------------------------------------------------------------
// RoPE + pack: qkv fp32 [Mrows][3072] -> qb bf16 [b][h][t][64] (scaled),
// kb bf16 [b][g][t][64].
// ---------------------------------------------------------------------------
__global__ void rope_pack_qk(const float* __restrict__ qkv,
                             const float* __restrict__ cosT,
                             const float* __restrict__ sinT,
                             short* __restrict__ qb, short* __restrict__ kb,
                             int total) {
    int idx = blockIdx.x * blockDim.x + threadIdx.x;
    if (idx >= total) return;
    int d   = idx & 31;
    int hh  = (idx >> 5) % 40;
    int row = idx / (32 * 40);
    int t   = row & (Tc - 1);
    int b   = row >> 11;
    float c = cosT[t * HDc + d];
    float s = sinT[t * HDc + d];
    if (hh < 32) {
        const float* p = qkv + (size_t)row * QKVW + hh * 64;
        float x0 = p[d], x1 = p[d + 32];
        short* qp = qb + (((size_t)(b * Hc + hh) * Tc + t) * 64);
        qp[d]      = f2bf((x0 * c - x1 * s) * SCALE);
        qp[d + 32] = f2bf((x1 * c + x0 * s) * SCALE);
    } else {
        int g = hh - 32;
        const float* p = qkv + (size_t)row * QKVW + 2048 + g * 64;
        float x0 = p[d], x1 = p[d + 32];
        short* kp = kb + (((size_t)(b * KVc + g) * Tc + t) * 64);
        kp[d]      = f2bf(x0 * c - x1 * s);
        kp[d + 32] = f2bf(x1 * c + x0 * s);
    }
}

// ---------------------------------------------------------------------------
// V transpose + convert: qkv fp32 v-section -> vtb bf16 [b][g][d][T].
// ---------------------------------------------------------------------------
__global__ __launch_bounds__(256) void pack_vt(const float* __restrict__ qkv,
                                               short* __restrict__ vtb) {
    __shared__ float T[64][68];
    const int t0 = blockIdx.x * 64;
    const int g  = blockIdx.y;
    const int b  = blockIdx.z;
    const int tt = threadIdx.x;
    const int c4 = (tt & 15) * 4;
    const int rr = tt >> 4;
    const float* src = qkv + 2560 + g * 64;
#pragma unroll
    for (int r = 0; r < 4; ++r) {
        int t = rr + 16 * r;
        float4 v = *(const float4*)(src + (size_t)(b * Tc + t0 + t) * QKVW + c4);
        *(float4*)&T[t][c4] = v;
    }
    __syncthreads();
    short* dst = vtb + ((size_t)(b * KVc + g) * 64) * Tc;
#pragma unroll
    for (int r = 0; r < 4; ++r) {
        int d = rr + 16 * r;
        short4v s;
        s[0] = f2bf(T[c4 + 0][d]); s[1] = f2bf(T[c4 + 1][d]);
        s[2] = f2bf(T[c4 + 2][d]); s[3] = f2bf(T[c4 + 3][d]);
        *(short4v*)(dst + (size_t)d * Tc + t0 + c4) = s;
    }
}

// ---------------------------------------------------------------------------
// bf16 MFMA flash attention, K/V-shared dual-tile waves.
// Each wave owns 32 consecutive queries = two 16-row MFMA tiles (A,B) that
// SHARE every K and V fragment load.  Per 64-key step: 16 shared loads feed
// 32 MFMAs; two independent softmax chains give ILP.  Block = 4 independent
// waves (no block barriers), balanced assignment {bx, 31-bx, 32+bx, 63-bx}.
// The per-wave P relay (LDS) is fenced with wave-level sched/wave barriers:
// cross-lane LDS exchange is only safe if ds_reads are emitted after the
// ds_writes (SIMT alias analysis may otherwise hoist them — round-8 race).
// ---------------------------------------------------------------------------
__global__ __launch_bounds__(256, 2) void attn_gqa(const short* __restrict__ qb,
                                                   const short* __restrict__ kb,
                                                   const short* __restrict__ vtb,
                                                   short* __restrict__ yb) {
    __shared__ short Ps[4][2][16][72];
    const int tid = threadIdx.x;
    const int l  = tid & 63;
    const int w  = tid >> 6;
    const int lr = l & 15;
    const int lg = l >> 4;
    const int bx = blockIdx.x;                 // 0..15
    const int a  = (w & 2) ? ((w & 1) ? 63 - bx : 32 + bx)
                           : ((w & 1) ? 31 - bx : bx);      // 0..63
    const int h  = blockIdx.y;
    const int b  = blockIdx.z;
    const int g  = h >> 2;
    const int qA = a * 32;                     // tile A rows qA.., B rows qA+16..

    const short* qhb = qb  + ((size_t)(b * Hc  + h) * Tc) * 64;
    const short* khb = kb  + ((size_t)(b * KVc + g) * Tc) * 64;
    const short* vhb = vtb + ((size_t)(b * KVc + g) * 64) * Tc;

    const bf16x8 qA0 = *(const bf16x8*)(qhb + (size_t)(qA + lr) * 64 + lg * 8);
    const bf16x8 qA1 = *(const bf16x8*)(qhb + (size_t)(qA + lr) * 64 + 32 + lg * 8);
    const bf16x8 qB0 = *(const bf16x8*)(qhb + (size_t)(qA + 16 + lr) * 64 + lg * 8);
    const bf16x8 qB1 = *(const bf16x8*)(qhb + (size_t)(qA + 16 + lr) * 64 + 32 + lg * 8);

    f32x4 oA[4], oB[4];
#pragma unroll
    for (int i = 0; i < 4; ++i) { oA[i] = f32x4{0.f,0.f,0.f,0.f}; oB[i] = f32x4{0.f,0.f,0.f,0.f}; }
    float mA[4], lA[4], mB[4], lB[4];
#pragma unroll
    for (int i = 0; i < 4; ++i) { mA[i] = -1e30f; lA[i] = 0.f; mB[i] = -1e30f; lB[i] = 0.f; }

    const int nsteps = ((qA + 31) >> 6) + 1;

    for (int st = 0; st < nsteps; ++st) {
        const int kv0 = st * 64;

        // ---- shared K fragments ----
        bf16x8 kf[8];
#pragma unroll
        for (int kbk = 0; kbk < 4; ++kbk) {
            const short* kr = khb + (size_t)(kv0 + 16 * kbk + lr) * 64;
            kf[2 * kbk]     = *(const bf16x8*)(kr + lg * 8);
            kf[2 * kbk + 1] = *(const bf16x8*)(kr + 32 + lg * 8);
        }

        // ---- S = Q K^T for both tiles from the same K frags ----
        f32x4 cA[4], cB[4];
#pragma unroll
        for (int kbk = 0; kbk < 4; ++kbk) {
            f32x4 acc = f32x4{0.f,0.f,0.f,0.f};
            acc = __builtin_amdgcn_mfma_f32_16x16x32_bf16(qA0, kf[2*kbk],   acc, 0, 0, 0);
            acc = __builtin_amdgcn_mfma_f32_16x16x32_bf16(qA1, kf[2*kbk+1], acc, 0, 0, 0);
            cA[kbk] = acc;
            f32x4 acb = f32x4{0.f,0.f,0.f,0.f};
            acb = __builtin_amdgcn_mfma_f32_16x16x32_bf16(qB0, kf[2*kbk],   acb, 0, 0, 0);
            acb = __builtin_amdgcn_mfma_f32_16x16x32_bf16(qB1, kf[2*kbk+1], acb, 0, 0, 0);
            cB[kbk] = acb;
        }

        if (st == nsteps - 1) {               // causal mask, diagonal step
#pragma unroll
            for (int kbk = 0; kbk < 4; ++kbk)
#pragma unroll
                for (int r = 0; r < 4; ++r) {
                    const int key = kv0 + lr + 16 * kbk;
                    if (key > qA + lg * 4 + r)      cA[kbk][r] = -1e30f;
                    if (key > qA + 16 + lg * 4 + r) cB[kbk][r] = -1e30f;
                }
        }

        // ---- online softmax, both tiles (independent chains -> ILP) ----
#pragma unroll
        for (int r = 0; r < 4; ++r) {
            float tA = fmaxf(fmaxf(cA[0][r], cA[1][r]), fmaxf(cA[2][r], cA[3][r]));
            float tB = fmaxf(fmaxf(cB[0][r], cB[1][r]), fmaxf(cB[2][r], cB[3][r]));
            tA = fmaxf(tA, __shfl_xor(tA, 1));  tB = fmaxf(tB, __shfl_xor(tB, 1));
            tA = fmaxf(tA, __shfl_xor(tA, 2));  tB = fmaxf(tB, __shfl_xor(tB, 2));
            tA = fmaxf(tA, __shfl_xor(tA, 4));  tB = fmaxf(tB, __shfl_xor(tB, 4));
            tA = fmaxf(tA, __shfl_xor(tA, 8));  tB = fmaxf(tB, __shfl_xor(tB, 8));
            if (tA > mA[r]) {
                const float corr = __expf(mA[r] - tA);
                mA[r] = tA; lA[r] *= corr;
#pragma unroll
                for (int db = 0; db < 4; ++db) oA[db][r] *= corr;
            }
            if (tB > mB[r]) {
                const float corr = __expf(mB[r] - tB);
                mB[r] = tB; lB[r] *= corr;
#pragma unroll
                for (int db = 0; db < 4; ++db) oB[db][r] *= corr;
            }
            float rA = 0.f, rB = 0.f;
#pragma unroll
            for (int kbk = 0; kbk < 4; ++kbk) {
                float pA = __expf(cA[kbk][r] - mA[r]);
                float pB = __expf(cB[kbk][r] - mB[r]);
                cA[kbk][r] = pA; rA += pA;
                cB[kbk][r] = pB; rB += pB;
            }
            rA += __shfl_xor(rA, 1);  rB += __shfl_xor(rB, 1);
            rA += __shfl_xor(rA, 2);  rB += __shfl_xor(rB, 2);
            rA += __shfl_xor(rA, 4);  rB += __shfl_xor(rB, 4);
            rA += __shfl_xor(rA, 8);  rB += __shfl_xor(rB, 8);
            lA[r] += rA;  lB[r] += rB;
#pragma unroll
            for (int kbk = 0; kbk < 4; ++kbk) {
                Ps[w][0][lg * 4 + r][lr + 16 * kbk] = f2bf(cA[kbk][r]);
                Ps[w][1][lg * 4 + r][lr + 16 * kbk] = f2bf(cB[kbk][r]);
            }
        }

        // ---- fence: all Ps writes must be emitted before the PV reads ----
        lds_fence();

        // ---- O += P V : shared V fragments feed both tiles ----
#pragma unroll
        for (int ks = 0; ks < 2; ++ks) {
            bf16x8 paA = *(const bf16x8*)&Ps[w][0][lr][lg * 8 + ks * 32];
            bf16x8 paB = *(const bf16x8*)&Ps[w][1][lr][lg * 8 + ks * 32];
#pragma unroll
            for (int db = 0; db < 4; ++db) {
                bf16x8 vv = *(const bf16x8*)(vhb + (size_t)(db * 16 + lr) * Tc
                                             + kv0 + ks * 32 + lg * 8);
                oA[db] = __builtin_amdgcn_mfma_f32_16x16x32_bf16(paA, vv, oA[db], 0, 0, 0);
                oB[db] = __builtin_amdgcn_mfma_f32_16x16x32_bf16(paB, vv, oB[db], 0, 0, 0);
            }
        }

        // ---- fence: PV reads done before next step's Ps writes ----
        lds_fence();
    }

    // ---- epilogue, both tiles ----
#pragma unroll
    for (int r = 0; r < 4; ++r) {
        const float iA = 1.0f / lA[r];
        const float iB = 1.0f / lB[r];
        short* ypA = yb + (size_t)(b * Tc + qA + lg * 4 + r) * Dc + h * 64;
        short* ypB = yb + (size_t)(b * Tc + qA + 16 + lg * 4 + r) * Dc + h * 64;
#pragma unroll
        for (int db = 0; db < 4; ++db) {
            ypA[lr + 16 * db] = f2bf(oA[db][r] * iA);
            ypB[lr + 16 * db] = f2bf(oB[db][r] * iB);
        }
    }
}

// ---------------------------------------------------------------------------
extern "C" void kernel_launch(void* const* d_in, const int* in_sizes, int n_in,
                              void* d_out, int out_size, void* d_ws, size_t ws_size,
                              hipStream_t stream) {
    const float* x    = (const float*)d_in[0];
    const float* Wq   = (const float*)d_in[1];
    const float* Wk   = (const float*)d_in[2];
    const float* Wv   = (const float*)d_in[3];
    const float* Wo   = (const float*)d_in[4];
    const float* cosT = (const float*)d_in[5];
    const float* sinT = (const float*)d_in[6];
    float* out = (float*)d_out;

    short* xb    = (short*)d_ws;                            // [4096,2048] bf16
    short* Wqkvt = xb + (size_t)Mrows * Dc;                 // [3072,2048] bf16
    short* Wot   = Wqkvt + (size_t)QKVW * Dc;               // [2048,2048] bf16
    short* ybuf  = Wot + (size_t)Dc * Dc;                   // [4096,2048] bf16
    float* qkv   = (float*)(ybuf + (size_t)Mrows * Dc);     // [4096,3072] f32
    short* qbp = xb;                                        // reuse after QKV GEMM
    short* kbp = Wqkvt;
    short* vtb = Wqkvt + (size_t)Bc * KVc * Tc * 64;

    conv_bf16<<<(Mrows * Dc / 8 + 255) / 256, 256, 0, stream>>>(x, xb, Mrows * Dc);
    transpose_conv<<<dim3(Dc / 64, Dc / 64), 256, 0, stream>>>(Wq, Wqkvt, Dc, Dc, 0);
    transpose_conv<<<dim3(512 / 64, Dc / 64), 256, 0, stream>>>(Wk, Wqkvt, 512, Dc, 2048);
    transpose_conv<<<dim3(512 / 64, Dc / 64), 256, 0, stream>>>(Wv, Wqkvt, 512, Dc, 2560);
    transpose_conv<<<dim3(Dc / 64, Dc / 64), 256, 0, stream>>>(Wo, Wot, Dc, Dc, 0);

    gemm_mfma<<<dim3(QKVW / 128, Mrows / 128), 256, 0, stream>>>(xb, Wqkvt, qkv, Mrows, QKVW, Dc);

    {
        int total = Mrows * (Hc + KVc) * 32;
        rope_pack_qk<<<(total + 255) / 256, 256, 0, stream>>>(qkv, cosT, sinT, qbp, kbp, total);
        pack_vt<<<dim3(Tc / 64, KVc, Bc), 256, 0, stream>>>(qkv, vtb);
    }

    // dual-tile waves: 16 blocks x 4 waves cover the 64 wave-pair slots
    attn_gqa<<<dim3(16, Hc, Bc), 256, 0, stream>>>(qbp, kbp, vtb, ybuf);

    gemm_mfma<<<dim3(Dc / 128, Mrows / 128), 256, 0, stream>>>(ybuf, Wot, out, Mrows, Dc, Dc);
}